// Round 11
// baseline (325.107 us; speedup 1.0000x reference)
//
#include <hip/hip_runtime.h>
#include <math.h>

// ---------------------------------------------------------------------------
// GCN: 3 layers (128->32->32->32). CSR build (hist/total/sbase/binoff/split/
// place — no scattered global stores, no redundant re-reads).
// Aggregation is COLUMN-SLICED: hps stored as 8 slices hs[q][N][4] fp16
// (800KB/slice). blockIdx&7 -> slice q ~ XCD: each XCD's gathers stay inside
// its own L2-resident slice (kills the 51MB random HBM fetch of row layout).
// One lane per node: 64 edge-gathers per wave instruction.
// Layer algebra: agg[g] = tanh( dis[g]*(sum_{e} hps[src_e] + hps[g]) + b ),
// hps = dis ⊙ (h @ W). Layer 2/3 transform = separate sliced GEMM (k_gemms).
// cat is sliced too: cat[layer][q][node][4] f32; k_head gathers accordingly.
// Assumes N <= 128000; harness uses N=100000, E=1.6M.
// ---------------------------------------------------------------------------

typedef int      int4v   __attribute__((ext_vector_type(4)));
typedef float    float4v __attribute__((ext_vector_type(4)));
typedef _Float16 half4v  __attribute__((ext_vector_type(4)));

#define NBLK 256            // blocks in hist/split
#define SB   500            // nodes per fine bin
#define CAPE 10240          // LDS stage capacity in k_place

__device__ inline float4v h2f(half4v h) {
    float4v f = { (float)h[0], (float)h[1], (float)h[2], (float)h[3] };
    return f;
}

// ---- per-block fine histogram ----
__global__ void k_hist(const int* __restrict__ dst, int* __restrict__ blk_hist,
                       int E, int NP) {
    __shared__ int h[256];
    for (int i = threadIdx.x; i < NP; i += 256) h[i] = 0;
    __syncthreads();
    const int4v* d4 = (const int4v*)dst;
    int nv = E >> 2;
    int stride = gridDim.x * blockDim.x;
    for (int i = blockIdx.x * blockDim.x + threadIdx.x; i < nv; i += stride) {
        int4v d = __builtin_nontemporal_load(&d4[i]);
#pragma unroll
        for (int j = 0; j < 4; ++j) atomicAdd(&h[d[j] / SB], 1);
    }
    if (blockIdx.x == 0) {
        for (int e = (nv << 2) + threadIdx.x; e < E; e += blockDim.x)
            atomicAdd(&h[dst[e] / SB], 1);
    }
    __syncthreads();
    for (int i = threadIdx.x; i < NP; i += 256)
        blk_hist[blockIdx.x * NP + i] = h[i];
}

__global__ void k_total(const int* __restrict__ blk_hist, int* __restrict__ total, int NP) {
    __shared__ int s[256];
    int f = blockIdx.x;
    int acc = 0;
    for (int b = threadIdx.x; b < NBLK; b += 256) acc += blk_hist[b * NP + f];
    s[threadIdx.x] = acc;
    __syncthreads();
    for (int off = 128; off > 0; off >>= 1) {
        if (threadIdx.x < off) s[threadIdx.x] += s[threadIdx.x + off];
        __syncthreads();
    }
    if (threadIdx.x == 0) total[f] = s[0];
}

__global__ void k_sbase(const int* __restrict__ total, int* __restrict__ sbase, int NP) {
    __shared__ int s[256];
    int t = threadIdx.x;
    int v = (t < NP) ? total[t] : 0;
    s[t] = v;
    __syncthreads();
    for (int off = 1; off < 256; off <<= 1) {
        int u = (t >= off) ? s[t - off] : 0;
        __syncthreads();
        s[t] += u;
        __syncthreads();
    }
    if (t < NP) sbase[t] = s[t] - v;
    if (t == NP - 1) sbase[NP] = s[t];
}

__global__ void k_binoff(const int* __restrict__ blk_hist, const int* __restrict__ sbase,
                         int* __restrict__ blk_off, int NP) {
    __shared__ int s[NBLK];
    int f = blockIdx.x;
    int b = threadIdx.x;
    int v = blk_hist[b * NP + f];
    s[b] = v;
    __syncthreads();
    for (int off = 1; off < NBLK; off <<= 1) {
        int u = (b >= off) ? s[b - off] : 0;
        __syncthreads();
        s[b] += u;
        __syncthreads();
    }
    blk_off[b * NP + f] = sbase[f] + s[b] - v;
}

__global__ void k_split(const int* __restrict__ src, const int* __restrict__ dst,
                        const int* __restrict__ blk_off, uint2* __restrict__ pairs,
                        int E, int NP) {
    __shared__ int goff[256];
    for (int f = threadIdx.x; f < NP; f += 256)
        goff[f] = blk_off[blockIdx.x * NP + f];
    __syncthreads();
    const int4v* d4 = (const int4v*)dst;
    const int4v* s4 = (const int4v*)src;
    int nv = E >> 2;
    int stride = gridDim.x * blockDim.x;
    for (int i = blockIdx.x * blockDim.x + threadIdx.x; i < nv; i += stride) {
        int4v d = __builtin_nontemporal_load(&d4[i]);
        int4v s = __builtin_nontemporal_load(&s4[i]);
#pragma unroll
        for (int j = 0; j < 4; ++j) {
            int f = d[j] / SB;
            int pos = atomicAdd(&goff[f], 1);
            pairs[pos] = make_uint2((unsigned)s[j], (unsigned)d[j]);
        }
    }
    if (blockIdx.x == 0) {
        for (int e = (nv << 2) + threadIdx.x; e < E; e += blockDim.x) {
            int f = dst[e] / SB;
            int pos = atomicAdd(&goff[f], 1);
            pairs[pos] = make_uint2((unsigned)src[e], (unsigned)dst[e]);
        }
    }
}

__global__ void __launch_bounds__(512)
k_place(const uint2* __restrict__ pairs, const int* __restrict__ sbase,
        int* __restrict__ rowptr, float* __restrict__ dis,
        int* __restrict__ csr_src, int N, int NP) {
    __shared__ int lcnt[SB];
    __shared__ int lrp[SB + 1];
    __shared__ int sc[512];
    __shared__ int stage[CAPE];
    int f = blockIdx.x;
    int lo = f * SB;
    if (lo >= N) return;
    int hi = lo + SB; if (hi > N) hi = N;
    int sbc = hi - lo;
    int p0 = sbase[f], p1 = sbase[f + 1];
    int base = p0;
    int tid = threadIdx.x;
    for (int i = tid; i < sbc; i += 512) lcnt[i] = 0;
    __syncthreads();
    {
        int i = p0 + tid;
        for (; i + 3 * 512 < p1; i += 4 * 512) {
            uint2 a = pairs[i], c = pairs[i + 512], d = pairs[i + 1024], e = pairs[i + 1536];
            unsigned la = a.y - lo, lc = c.y - lo, ld = d.y - lo, le = e.y - lo;
            if (la < (unsigned)sbc) atomicAdd(&lcnt[la], 1);
            if (lc < (unsigned)sbc) atomicAdd(&lcnt[lc], 1);
            if (ld < (unsigned)sbc) atomicAdd(&lcnt[ld], 1);
            if (le < (unsigned)sbc) atomicAdd(&lcnt[le], 1);
        }
        for (; i < p1; i += 512) {
            unsigned ly = pairs[i].y - lo;
            if (ly < (unsigned)sbc) atomicAdd(&lcnt[ly], 1);
        }
    }
    __syncthreads();
    for (int i = tid; i < sbc; i += 512) dis[lo + i] = rsqrtf(1.0f + (float)lcnt[i]);
    int v = (tid < sbc) ? lcnt[tid] : 0;
    sc[tid] = v;
    __syncthreads();
    for (int off = 1; off < 512; off <<= 1) {
        int u = (tid >= off) ? sc[tid - off] : 0;
        __syncthreads();
        sc[tid] += u;
        __syncthreads();
    }
    if (tid < sbc) lrp[tid] = sc[tid] - v;
    if (tid == 511) lrp[sbc] = sc[511];
    __syncthreads();
    int T = lrp[sbc];
    for (int i = tid; i < sbc; i += 512) rowptr[lo + i] = base + lrp[i];
    if (hi == N && tid == 0) rowptr[N] = base + T;
    for (int i = tid; i < sbc; i += 512) lcnt[i] = 0;
    __syncthreads();
    {
        int i = p0 + tid;
        for (; i + 3 * 512 < p1; i += 4 * 512) {
            uint2 a = pairs[i], c = pairs[i + 512], d = pairs[i + 1024], e = pairs[i + 1536];
#pragma unroll
            for (int j = 0; j < 4; ++j) {
                uint2 p = (j == 0) ? a : (j == 1) ? c : (j == 2) ? d : e;
                unsigned ly = p.y - lo;
                if (ly < (unsigned)sbc) {
                    int slot = lrp[ly] + atomicAdd(&lcnt[ly], 1);
                    if (T <= CAPE) stage[slot] = (int)p.x;
                    else           csr_src[base + slot] = (int)p.x;
                }
            }
        }
        for (; i < p1; i += 512) {
            uint2 p = pairs[i];
            unsigned ly = p.y - lo;
            if (ly < (unsigned)sbc) {
                int slot = lrp[ly] + atomicAdd(&lcnt[ly], 1);
                if (T <= CAPE) stage[slot] = (int)p.x;
                else           csr_src[base + slot] = (int)p.x;
            }
        }
    }
    __syncthreads();
    if (T <= CAPE)
        for (int j = tid; j < T; j += 512) csr_src[base + j] = stage[j];
}

// ---- layer-1 GEMM: hs[q][row][4] = fp16( dis ⊙ (x[row,128] @ W[128,32]) ) ----
__global__ void k_gemm1(const float* __restrict__ h, const float* __restrict__ W,
                        const float* __restrict__ dis, _Float16* __restrict__ hs, int n) {
    __shared__ float sW[128 * 32];
    __shared__ float sh[64 * 132];
    int tid = threadIdx.x;
    int row0 = blockIdx.x * 64;
    for (int j = tid; j < 1024; j += 128)
        *(float4*)&sW[j * 4] = *(const float4*)&W[j * 4];
    for (int j = tid; j < 2048; j += 128) {
        int r = j >> 5, c4 = j & 31;
        float4v v = {0.f, 0.f, 0.f, 0.f};
        if (row0 + r < n)
            v = __builtin_nontemporal_load((const float4v*)&h[(size_t)(row0 + r) * 128 + c4 * 4]);
        *(float4v*)&sh[r * 132 + c4 * 4] = v;
    }
    __syncthreads();
    int rg = tid >> 3;
    int cg = tid & 7;       // == slice q
    float acc[4][4] = {};
    const float* shp = &sh[(rg * 4) * 132];
    const float* swp = &sW[cg * 4];
#pragma unroll 8
    for (int k4 = 0; k4 < 32; ++k4) {
        float4 hv[4], wv[4];
#pragma unroll
        for (int r = 0; r < 4; ++r) hv[r] = *(const float4*)&shp[r * 132 + k4 * 4];
#pragma unroll
        for (int t = 0; t < 4; ++t) wv[t] = *(const float4*)&swp[(k4 * 4 + t) * 32];
#pragma unroll
        for (int r = 0; r < 4; ++r) {
            const float hr[4] = {hv[r].x, hv[r].y, hv[r].z, hv[r].w};
#pragma unroll
            for (int t = 0; t < 4; ++t) {
                acc[r][0] += hr[t] * wv[t].x;
                acc[r][1] += hr[t] * wv[t].y;
                acc[r][2] += hr[t] * wv[t].z;
                acc[r][3] += hr[t] * wv[t].w;
            }
        }
    }
#pragma unroll
    for (int r = 0; r < 4; ++r) {
        int row = row0 + rg * 4 + r;
        if (row < n) {
            float dv = dis[row];
            half4v o = { (_Float16)(acc[r][0] * dv), (_Float16)(acc[r][1] * dv),
                         (_Float16)(acc[r][2] * dv), (_Float16)(acc[r][3] * dv) };
            *(half4v*)&hs[((size_t)cg * n + row) * 4] = o;
        }
    }
}

// ---- sliced aggregation: one lane per node, slice q = blockIdx&7 (~XCD) ----
__global__ void k_aggs(const _Float16* __restrict__ hs, const int* __restrict__ rowptr,
                       const int* __restrict__ csr_src, const float* __restrict__ dis,
                       const float* __restrict__ bias, float* __restrict__ catl, int N) {
    int q = blockIdx.x & 7;
    int g = (blockIdx.x >> 3) * blockDim.x + threadIdx.x;
    if (g >= N) return;
    const half4v* hq = (const half4v*)(hs + (size_t)q * N * 4);
    float4v acc = h2f(hq[g]);                       // self term
    int e = rowptr[g], e1 = rowptr[g + 1];
    for (; e + 4 <= e1; e += 4) {
        int s0 = csr_src[e],     s1 = csr_src[e + 1];
        int s2 = csr_src[e + 2], s3 = csr_src[e + 3];
        half4v h0 = hq[s0], h1 = hq[s1], h2 = hq[s2], h3 = hq[s3];
        acc += (h2f(h0) + h2f(h1)) + (h2f(h2) + h2f(h3));
    }
    for (; e < e1; ++e) acc += h2f(hq[csr_src[e]]);
    float dg = dis[g];
    float4v bb = *(const float4v*)&bias[q * 4];
    float4v v;
    v[0] = tanhf(dg * acc[0] + bb[0]);
    v[1] = tanhf(dg * acc[1] + bb[1]);
    v[2] = tanhf(dg * acc[2] + bb[2]);
    v[3] = tanhf(dg * acc[3] + bb[3]);
    *(float4v*)&catl[((size_t)q * N + g) * 4] = v;
}

// ---- sliced 32x32 transform: hout[q][g][4] = fp16(dis ⊙ (cat_l @ W)) ----
__global__ void k_gemms(const float* __restrict__ catl, const float* __restrict__ W,
                        const float* __restrict__ dis, _Float16* __restrict__ hout, int N) {
    __shared__ float sW[32 * 32];
    __shared__ float sv[32][33];
    int tid = threadIdx.x;
    int g0 = blockIdx.x * 32;
    for (int i = tid; i < 1024; i += 256) sW[i] = W[i];
    {
        int qq = tid >> 5, i = tid & 31;
        int g = g0 + i;
        float4v vv = {0.f, 0.f, 0.f, 0.f};
        if (g < N) vv = *(const float4v*)&catl[((size_t)qq * N + g) * 4];
        sv[i][qq * 4 + 0] = vv[0]; sv[i][qq * 4 + 1] = vv[1];
        sv[i][qq * 4 + 2] = vv[2]; sv[i][qq * 4 + 3] = vv[3];
    }
    __syncthreads();
    int r = tid >> 3, cg = tid & 7;
    float a0 = 0.f, a1 = 0.f, a2 = 0.f, a3 = 0.f;
#pragma unroll 8
    for (int k = 0; k < 32; ++k) {
        float hv = sv[r][k];
        const float* wp = &sW[k * 32 + cg * 4];
        a0 += hv * wp[0]; a1 += hv * wp[1]; a2 += hv * wp[2]; a3 += hv * wp[3];
    }
    int g = g0 + r;
    if (g < N) {
        float dv = dis[g];
        half4v o = { (_Float16)(a0 * dv), (_Float16)(a1 * dv),
                     (_Float16)(a2 * dv), (_Float16)(a3 * dv) };
        *(half4v*)&hout[((size_t)cg * N + g) * 4] = o;
    }
}

__global__ void k_idx(const int* __restrict__ batch, int* __restrict__ idx, int n, int g) {
    int i = blockIdx.x * blockDim.x + threadIdx.x;
    if (i >= g) return;
    int lo = 0, hi = n;
    while (lo < hi) {
        int mid = (lo + hi) >> 1;
        if (batch[mid] < i) lo = mid + 1; else hi = mid;
    }
    idx[i] = lo;
}

// per graph: gv[96] (sliced cat gather) -> hidden[128] relu -> 2 logits -> lsm
__global__ void k_head(const float* __restrict__ cat, const int* __restrict__ idx,
                       const float* __restrict__ w1, const float* __restrict__ b1,
                       const float* __restrict__ w2, const float* __restrict__ b2,
                       float* __restrict__ out, int N) {
    __shared__ float gv[96];
    __shared__ float s0[128];
    __shared__ float s1[128];
    int g = blockIdx.x, t = threadIdx.x;
    int node = idx[g];
    if (t < 96) {
        int l = t >> 5, rem = t & 31, qq = rem >> 2, c = rem & 3;
        gv[t] = cat[(((size_t)l * 8 + qq) * N + node) * 4 + c];
    }
    __syncthreads();
    float acc = b1[t];
#pragma unroll 8
    for (int i = 0; i < 96; ++i) acc += gv[i] * w1[i * 128 + t];
    float h = fmaxf(acc, 0.0f);
    s0[t] = h * w2[t * 2 + 0];
    s1[t] = h * w2[t * 2 + 1];
    __syncthreads();
    for (int off = 64; off > 0; off >>= 1) {
        if (t < off) { s0[t] += s0[t + off]; s1[t] += s1[t + off]; }
        __syncthreads();
    }
    if (t == 0) {
        float l0 = s0[0] + b2[0];
        float l1 = s1[0] + b2[1];
        float m  = fmaxf(l0, l1);
        float lse = m + logf(expf(l0 - m) + expf(l1 - m));
        out[(size_t)g * 2 + 0] = l0 - lse;
        out[(size_t)g * 2 + 1] = l1 - lse;
    }
}

extern "C" void kernel_launch(void* const* d_in, const int* in_sizes, int n_in,
                              void* d_out, int out_size, void* d_ws, size_t ws_size,
                              hipStream_t stream) {
    const float* x    = (const float*)d_in[0];
    const int*   ei   = (const int*)d_in[1];
    const int*   batch= (const int*)d_in[2];
    const float* W1   = (const float*)d_in[4];
    const float* b1   = (const float*)d_in[5];
    const float* W2   = (const float*)d_in[6];
    const float* b2   = (const float*)d_in[7];
    const float* W3   = (const float*)d_in[8];
    const float* b3   = (const float*)d_in[9];
    const float* l1w  = (const float*)d_in[10];
    const float* l1b  = (const float*)d_in[11];
    const float* l2w  = (const float*)d_in[12];
    const float* l2b  = (const float*)d_in[13];
    float* out = (float*)d_out;

    const int N = in_sizes[0] / 128;
    const int E = in_sizes[1] / 2;
    const int G = out_size / 2;
    const int* src = ei;
    const int* dst = ei + E;

    const int NP = (N + SB - 1) / SB;

    char* w = (char*)d_ws;
    auto alloc = [&](size_t bytes) {
        char* p = w;
        w += (bytes + 255) & ~(size_t)255;
        return p;
    };
    float*    dis      = (float*)   alloc((size_t)N * 4);
    int*      rowptr   = (int*)     alloc((size_t)(N + 1) * 4);
    int*      csr_src  = (int*)     alloc((size_t)E * 4);
    int*      blk_hist = (int*)     alloc((size_t)NBLK * NP * 4);
    int*      total    = (int*)     alloc((size_t)NP * 4);
    int*      sbase    = (int*)     alloc((size_t)(NP + 1) * 4);
    int*      blk_off  = (int*)     alloc((size_t)NBLK * NP * 4);
    uint2*    pairs    = (uint2*)   alloc((size_t)E * 8);
    _Float16* hsA      = (_Float16*)alloc((size_t)N * 32 * 2);
    _Float16* hsB      = (_Float16*)alloc((size_t)N * 32 * 2);
    float*    catb     = (float*)   alloc((size_t)N * 96 * 4);
    int*      idx      = (int*)     alloc((size_t)G * 4);

    const int gemm_bl  = (N + 63) / 64;
    const int aggs_bl  = ((N + 255) / 256) * 8;   // 8 slices
    const int gemms_bl = (N + 31) / 32;
    const size_t LSTRIDE = (size_t)N * 32;        // cat floats per layer

    k_hist  <<<NBLK, 256, 0, stream>>>(dst, blk_hist, E, NP);
    k_total <<<NP,   256, 0, stream>>>(blk_hist, total, NP);
    k_sbase <<<1,    256, 0, stream>>>(total, sbase, NP);
    k_binoff<<<NP,  NBLK, 0, stream>>>(blk_hist, sbase, blk_off, NP);
    k_split <<<NBLK, 256, 0, stream>>>(src, dst, blk_off, pairs, E, NP);
    k_place <<<NP,   512, 0, stream>>>(pairs, sbase, rowptr, dis, csr_src, N, NP);

    k_gemm1<<<gemm_bl, 128, 0, stream>>>(x, W1, dis, hsA, N);
    k_aggs <<<aggs_bl, 256, 0, stream>>>(hsA, rowptr, csr_src, dis, b1, catb + 0 * LSTRIDE, N);
    k_gemms<<<gemms_bl, 256, 0, stream>>>(catb + 0 * LSTRIDE, W2, dis, hsB, N);
    k_aggs <<<aggs_bl, 256, 0, stream>>>(hsB, rowptr, csr_src, dis, b2, catb + 1 * LSTRIDE, N);
    k_gemms<<<gemms_bl, 256, 0, stream>>>(catb + 1 * LSTRIDE, W3, dis, hsA, N);
    k_aggs <<<aggs_bl, 256, 0, stream>>>(hsA, rowptr, csr_src, dis, b3, catb + 2 * LSTRIDE, N);

    k_idx<<<(G + 255) / 256, 256, 0, stream>>>(batch, idx, N, G);
    k_head<<<G, 128, 0, stream>>>(catb, idx, l1w, l1b, l2w, l2b, out, N);
}

// Round 12
// 228.859 us; speedup vs baseline: 1.4206x; 1.4206x over previous
//
#include <hip/hip_runtime.h>
#include <math.h>

// ---------------------------------------------------------------------------
// GCN: 3 layers (128->32->32->32). CSR build with NO scattered global stores
// (hist/total/sbase/binoff/split/place, pairs PACKED to 4B: src<<9 | dst_local).
// Aggregation: fp16 hps row-gather (64B/edge), 32-lane group per node,
// 16-deep batched gathers; layer-2/3 GEMM fused into agg epilogue.
// Algebra: agg[g] = tanh( dis[g]*(sum_{e:dst=g} hps[src_e] + hps[g]) + b ),
//          hps = dis ⊙ (h @ W).
// Assumes N <= 128000 (fine bins <= 256, src < 2^17 * wait: src < N <= 128000
// fits 17 bits; SB=500 < 512 -> 9 bits). Harness: N=100000, E=1.6M.
// ---------------------------------------------------------------------------

typedef int      int4v   __attribute__((ext_vector_type(4)));
typedef float    float4v __attribute__((ext_vector_type(4)));
typedef _Float16 half4v  __attribute__((ext_vector_type(4)));

#define NBLK 256            // blocks in hist/split
#define SB   500            // nodes per fine bin
#define CAPE 10240          // LDS stage capacity (bin mean 8000, std ~90)

// ---- per-block fine histogram: blk_hist[b*NP + f] ----
__global__ void k_hist(const int* __restrict__ dst, int* __restrict__ blk_hist,
                       int E, int NP) {
    __shared__ int h[256];
    for (int i = threadIdx.x; i < NP; i += 256) h[i] = 0;
    __syncthreads();
    const int4v* d4 = (const int4v*)dst;
    int nv = E >> 2;
    int stride = gridDim.x * blockDim.x;
    for (int i = blockIdx.x * blockDim.x + threadIdx.x; i < nv; i += stride) {
        int4v d = __builtin_nontemporal_load(&d4[i]);
#pragma unroll
        for (int j = 0; j < 4; ++j) atomicAdd(&h[d[j] / SB], 1);
    }
    if (blockIdx.x == 0) {
        for (int e = (nv << 2) + threadIdx.x; e < E; e += blockDim.x)
            atomicAdd(&h[dst[e] / SB], 1);
    }
    __syncthreads();
    for (int i = threadIdx.x; i < NP; i += 256)
        blk_hist[blockIdx.x * NP + i] = h[i];
}

// ---- per-bin totals ----
__global__ void k_total(const int* __restrict__ blk_hist, int* __restrict__ total, int NP) {
    __shared__ int s[256];
    int f = blockIdx.x;
    int acc = 0;
    for (int b = threadIdx.x; b < NBLK; b += 256) acc += blk_hist[b * NP + f];
    s[threadIdx.x] = acc;
    __syncthreads();
    for (int off = 128; off > 0; off >>= 1) {
        if (threadIdx.x < off) s[threadIdx.x] += s[threadIdx.x + off];
        __syncthreads();
    }
    if (threadIdx.x == 0) total[f] = s[0];
}

// ---- exclusive scan of totals -> sbase[0..NP] ----
__global__ void k_sbase(const int* __restrict__ total, int* __restrict__ sbase, int NP) {
    __shared__ int s[256];
    int t = threadIdx.x;
    int v = (t < NP) ? total[t] : 0;
    s[t] = v;
    __syncthreads();
    for (int off = 1; off < 256; off <<= 1) {
        int u = (t >= off) ? s[t - off] : 0;
        __syncthreads();
        s[t] += u;
        __syncthreads();
    }
    if (t < NP) sbase[t] = s[t] - v;
    if (t == NP - 1) sbase[NP] = s[t];
}

// ---- per-(block,bin) window offsets ----
__global__ void k_binoff(const int* __restrict__ blk_hist, const int* __restrict__ sbase,
                         int* __restrict__ blk_off, int NP) {
    __shared__ int s[NBLK];
    int f = blockIdx.x;
    int b = threadIdx.x;
    int v = blk_hist[b * NP + f];
    s[b] = v;
    __syncthreads();
    for (int off = 1; off < NBLK; off <<= 1) {
        int u = (b >= off) ? s[b - off] : 0;
        __syncthreads();
        s[b] += u;
        __syncthreads();
    }
    blk_off[b * NP + f] = sbase[f] + s[b] - v;
}

// ---- scatter PACKED edges ((src<<9)|dst_local) into fine-bin regions ----
__global__ void k_split(const int* __restrict__ src, const int* __restrict__ dst,
                        const int* __restrict__ blk_off, unsigned* __restrict__ pairs,
                        int E, int NP) {
    __shared__ int goff[256];
    for (int f = threadIdx.x; f < NP; f += 256)
        goff[f] = blk_off[blockIdx.x * NP + f];
    __syncthreads();
    const int4v* d4 = (const int4v*)dst;
    const int4v* s4 = (const int4v*)src;
    int nv = E >> 2;
    int stride = gridDim.x * blockDim.x;
    for (int i = blockIdx.x * blockDim.x + threadIdx.x; i < nv; i += stride) {
        int4v d = __builtin_nontemporal_load(&d4[i]);
        int4v s = __builtin_nontemporal_load(&s4[i]);
#pragma unroll
        for (int j = 0; j < 4; ++j) {
            int f = d[j] / SB;
            int pos = atomicAdd(&goff[f], 1);
            pairs[pos] = ((unsigned)s[j] << 9) | (unsigned)(d[j] - f * SB);
        }
    }
    if (blockIdx.x == 0) {
        for (int e = (nv << 2) + threadIdx.x; e < E; e += blockDim.x) {
            int f = dst[e] / SB;
            int pos = atomicAdd(&goff[f], 1);
            pairs[pos] = ((unsigned)src[e] << 9) | (unsigned)(dst[e] - f * SB);
        }
    }
}

// ---- place: per fine bin, LDS count/scan/scatter, coalesced global writes ----
__global__ void __launch_bounds__(512)
k_place(const unsigned* __restrict__ pairs, const int* __restrict__ sbase,
        int* __restrict__ rowptr, float* __restrict__ dis,
        int* __restrict__ csr_src, int N, int NP) {
    __shared__ int lcnt[SB];
    __shared__ int lrp[SB + 1];
    __shared__ int sc[512];
    __shared__ int stage[CAPE];
    int f = blockIdx.x;
    int lo = f * SB;
    if (lo >= N) return;
    int hi = lo + SB; if (hi > N) hi = N;
    int sbc = hi - lo;
    int p0 = sbase[f], p1 = sbase[f + 1];
    int base = p0;
    int tid = threadIdx.x;
    for (int i = tid; i < sbc; i += 512) lcnt[i] = 0;
    __syncthreads();
    // pass A: count (4-way unrolled for MLP)
    {
        int i = p0 + tid;
        for (; i + 3 * 512 < p1; i += 4 * 512) {
            unsigned a = pairs[i], c = pairs[i + 512], d = pairs[i + 1024], e = pairs[i + 1536];
            atomicAdd(&lcnt[a & 511u], 1);
            atomicAdd(&lcnt[c & 511u], 1);
            atomicAdd(&lcnt[d & 511u], 1);
            atomicAdd(&lcnt[e & 511u], 1);
        }
        for (; i < p1; i += 512) atomicAdd(&lcnt[pairs[i] & 511u], 1);
    }
    __syncthreads();
    // dis (coalesced)
    for (int i = tid; i < sbc; i += 512) dis[lo + i] = rsqrtf(1.0f + (float)lcnt[i]);
    // exclusive scan lcnt -> lrp
    int v = (tid < sbc) ? lcnt[tid] : 0;
    sc[tid] = v;
    __syncthreads();
    for (int off = 1; off < 512; off <<= 1) {
        int u = (tid >= off) ? sc[tid - off] : 0;
        __syncthreads();
        sc[tid] += u;
        __syncthreads();
    }
    if (tid < sbc) lrp[tid] = sc[tid] - v;
    if (tid == 511) lrp[sbc] = sc[511];
    __syncthreads();
    int T = lrp[sbc];
    // rowptr (coalesced)
    for (int i = tid; i < sbc; i += 512) rowptr[lo + i] = base + lrp[i];
    if (hi == N && tid == 0) rowptr[N] = base + T;
    // pass B: scatter into LDS stage (or global fallback if T > CAPE)
    for (int i = tid; i < sbc; i += 512) lcnt[i] = 0;
    __syncthreads();
    {
        int i = p0 + tid;
        for (; i + 3 * 512 < p1; i += 4 * 512) {
            unsigned pk[4] = { pairs[i], pairs[i + 512], pairs[i + 1024], pairs[i + 1536] };
#pragma unroll
            for (int j = 0; j < 4; ++j) {
                unsigned ly = pk[j] & 511u;
                int slot = lrp[ly] + atomicAdd(&lcnt[ly], 1);
                if (T <= CAPE) stage[slot] = (int)(pk[j] >> 9);
                else           csr_src[base + slot] = (int)(pk[j] >> 9);
            }
        }
        for (; i < p1; i += 512) {
            unsigned p = pairs[i];
            unsigned ly = p & 511u;
            int slot = lrp[ly] + atomicAdd(&lcnt[ly], 1);
            if (T <= CAPE) stage[slot] = (int)(p >> 9);
            else           csr_src[base + slot] = (int)(p >> 9);
        }
    }
    __syncthreads();
    if (T <= CAPE)
        for (int j = tid; j < T; j += 512) csr_src[base + j] = stage[j];
}

// ---- layer-1 GEMM: hps[n,32] = fp16( dis ⊙ (x[n,128] @ W[128,32]) ) ----
__global__ void k_gemm1(const float* __restrict__ h, const float* __restrict__ W,
                        const float* __restrict__ dis, _Float16* __restrict__ hps, int n) {
    __shared__ float sW[128 * 32];          // [k][col]
    __shared__ float sh[64 * 132];          // [row][k], pad 132
    int tid = threadIdx.x;
    int row0 = blockIdx.x * 64;
    for (int j = tid; j < 1024; j += 128)
        *(float4*)&sW[j * 4] = *(const float4*)&W[j * 4];
    for (int j = tid; j < 2048; j += 128) {
        int r = j >> 5, c4 = j & 31;
        float4v v = {0.f, 0.f, 0.f, 0.f};
        if (row0 + r < n)
            v = __builtin_nontemporal_load((const float4v*)&h[(size_t)(row0 + r) * 128 + c4 * 4]);
        *(float4v*)&sh[r * 132 + c4 * 4] = v;
    }
    __syncthreads();
    int rg = tid >> 3;      // 0..15 -> 4 rows each
    int cg = tid & 7;       // 0..7  -> 4 cols each
    float acc[4][4] = {};
    const float* shp = &sh[(rg * 4) * 132];
    const float* swp = &sW[cg * 4];
#pragma unroll 8
    for (int k4 = 0; k4 < 32; ++k4) {
        float4 hv[4], wv[4];
#pragma unroll
        for (int r = 0; r < 4; ++r) hv[r] = *(const float4*)&shp[r * 132 + k4 * 4];
#pragma unroll
        for (int t = 0; t < 4; ++t) wv[t] = *(const float4*)&swp[(k4 * 4 + t) * 32];
#pragma unroll
        for (int r = 0; r < 4; ++r) {
            const float hr[4] = {hv[r].x, hv[r].y, hv[r].z, hv[r].w};
#pragma unroll
            for (int t = 0; t < 4; ++t) {
                acc[r][0] += hr[t] * wv[t].x;
                acc[r][1] += hr[t] * wv[t].y;
                acc[r][2] += hr[t] * wv[t].z;
                acc[r][3] += hr[t] * wv[t].w;
            }
        }
    }
#pragma unroll
    for (int r = 0; r < 4; ++r) {
        int row = row0 + rg * 4 + r;
        if (row < n) {
            float dv = dis[row];
            half4v o = { (_Float16)(acc[r][0] * dv), (_Float16)(acc[r][1] * dv),
                         (_Float16)(acc[r][2] * dv), (_Float16)(acc[r][3] * dv) };
            *(half4v*)&hps[(size_t)row * 32 + cg * 4] = o;
        }
    }
}

// ---- aggregation (+ optional fused next-layer GEMM epilogue) ----
// 32-lane group per node; 16-deep batched fp16 row gathers, f32 accum.
template <bool FUSE>
__global__ void k_agg(const _Float16* __restrict__ hps, const int* __restrict__ rowptr,
                      const int* __restrict__ csr_src, const float* __restrict__ dis,
                      const float* __restrict__ bias, float* __restrict__ outc,
                      int n, const float* __restrict__ Wn, _Float16* __restrict__ hpsn) {
    __shared__ float sW[32 * 32];
    if (FUSE) {
        for (int i = threadIdx.x; i < 1024; i += 256) sW[i] = Wn[i];
        __syncthreads();
    }
    int g    = (blockIdx.x * blockDim.x + threadIdx.x) >> 5;
    int lane = threadIdx.x & 31;
    if (g >= n) return;
    float acc = (float)hps[(size_t)g * 32 + lane];   // self term
    int e0 = rowptr[g], e1 = rowptr[g + 1];
    int e = e0;
    while (e < e1) {
        int m = e1 - e; if (m > 32) m = 32;
        int sv = (e + lane < e1) ? __builtin_nontemporal_load(&csr_src[e + lane]) : 0;
        int k = 0;
        for (; k + 16 <= m; k += 16) {
            float v[16];
#pragma unroll
            for (int j = 0; j < 16; ++j) {
                int s = __shfl(sv, k + j, 32);
                v[j] = (float)hps[(size_t)s * 32 + lane];
            }
            float a = ((v[0] + v[1]) + (v[2] + v[3])) + ((v[4] + v[5]) + (v[6] + v[7]));
            float b = ((v[8] + v[9]) + (v[10] + v[11])) + ((v[12] + v[13]) + (v[14] + v[15]));
            acc += a + b;
        }
        for (; k + 8 <= m; k += 8) {
            float v[8];
#pragma unroll
            for (int j = 0; j < 8; ++j) {
                int s = __shfl(sv, k + j, 32);
                v[j] = (float)hps[(size_t)s * 32 + lane];
            }
            acc += ((v[0] + v[1]) + (v[2] + v[3])) + ((v[4] + v[5]) + (v[6] + v[7]));
        }
        if (k + 4 <= m) {
            float v[4];
#pragma unroll
            for (int j = 0; j < 4; ++j) {
                int s = __shfl(sv, k + j, 32);
                v[j] = (float)hps[(size_t)s * 32 + lane];
            }
            acc += (v[0] + v[1]) + (v[2] + v[3]);
            k += 4;
        }
        for (; k < m; ++k) {
            int s = __shfl(sv, k, 32);
            acc += (float)hps[(size_t)s * 32 + lane];
        }
        e += m;
    }
    float dg = dis[g];
    float v = tanhf(dg * acc + bias[lane]);
    __builtin_nontemporal_store(v, &outc[(size_t)g * 96 + lane]);
    if (FUSE) {
        float a2 = 0.0f;
#pragma unroll
        for (int k = 0; k < 32; ++k)
            a2 += __shfl(v, k, 32) * sW[k * 32 + lane];
        hpsn[(size_t)g * 32 + lane] = (_Float16)(dg * a2);
    }
}

__global__ void k_idx(const int* __restrict__ batch, int* __restrict__ idx, int n, int g) {
    int i = blockIdx.x * blockDim.x + threadIdx.x;
    if (i >= g) return;
    int lo = 0, hi = n;
    while (lo < hi) {
        int mid = (lo + hi) >> 1;
        if (batch[mid] < i) lo = mid + 1; else hi = mid;
    }
    idx[i] = lo;
}

__global__ void k_head(const float* __restrict__ cat, const int* __restrict__ idx,
                       const float* __restrict__ w1, const float* __restrict__ b1,
                       const float* __restrict__ w2, const float* __restrict__ b2,
                       float* __restrict__ out) {
    __shared__ float gv[96];
    __shared__ float s0[128];
    __shared__ float s1[128];
    int g = blockIdx.x, t = threadIdx.x;
    int node = idx[g];
    if (t < 96) gv[t] = cat[(size_t)node * 96 + t];
    __syncthreads();
    float acc = b1[t];
#pragma unroll 8
    for (int i = 0; i < 96; ++i) acc += gv[i] * w1[i * 128 + t];
    float h = fmaxf(acc, 0.0f);
    s0[t] = h * w2[t * 2 + 0];
    s1[t] = h * w2[t * 2 + 1];
    __syncthreads();
    for (int off = 64; off > 0; off >>= 1) {
        if (t < off) { s0[t] += s0[t + off]; s1[t] += s1[t + off]; }
        __syncthreads();
    }
    if (t == 0) {
        float l0 = s0[0] + b2[0];
        float l1 = s1[0] + b2[1];
        float m  = fmaxf(l0, l1);
        float lse = m + logf(expf(l0 - m) + expf(l1 - m));
        out[(size_t)g * 2 + 0] = l0 - lse;
        out[(size_t)g * 2 + 1] = l1 - lse;
    }
}

extern "C" void kernel_launch(void* const* d_in, const int* in_sizes, int n_in,
                              void* d_out, int out_size, void* d_ws, size_t ws_size,
                              hipStream_t stream) {
    const float* x    = (const float*)d_in[0];
    const int*   ei   = (const int*)d_in[1];
    const int*   batch= (const int*)d_in[2];
    const float* W1   = (const float*)d_in[4];
    const float* b1   = (const float*)d_in[5];
    const float* W2   = (const float*)d_in[6];
    const float* b2   = (const float*)d_in[7];
    const float* W3   = (const float*)d_in[8];
    const float* b3   = (const float*)d_in[9];
    const float* l1w  = (const float*)d_in[10];
    const float* l1b  = (const float*)d_in[11];
    const float* l2w  = (const float*)d_in[12];
    const float* l2b  = (const float*)d_in[13];
    float* out = (float*)d_out;

    const int N = in_sizes[0] / 128;
    const int E = in_sizes[1] / 2;
    const int G = out_size / 2;
    const int* src = ei;
    const int* dst = ei + E;

    const int NP = (N + SB - 1) / SB;     // fine-bin count (=200 for N=100000)

    char* w = (char*)d_ws;
    auto alloc = [&](size_t bytes) {
        char* p = w;
        w += (bytes + 255) & ~(size_t)255;
        return p;
    };
    float*    dis      = (float*)   alloc((size_t)N * 4);
    int*      rowptr   = (int*)     alloc((size_t)(N + 1) * 4);
    int*      csr_src  = (int*)     alloc((size_t)E * 4);
    int*      blk_hist = (int*)     alloc((size_t)NBLK * NP * 4);
    int*      total    = (int*)     alloc((size_t)NP * 4);
    int*      sbase    = (int*)     alloc((size_t)(NP + 1) * 4);
    int*      blk_off  = (int*)     alloc((size_t)NBLK * NP * 4);
    unsigned* pairs    = (unsigned*)alloc((size_t)E * 4);
    _Float16* hpsA     = (_Float16*)alloc((size_t)N * 32 * 2);
    _Float16* hpsB     = (_Float16*)alloc((size_t)N * 32 * 2);
    float*    catb     = (float*)   alloc((size_t)N * 96 * 4);
    int*      idx      = (int*)     alloc((size_t)G * 4);

    const int nodes_bl = (N * 32 + 255) / 256;   // 8 nodes per 256-thr block
    const int gemm_bl  = (N + 63) / 64;

    k_hist  <<<NBLK, 256, 0, stream>>>(dst, blk_hist, E, NP);
    k_total <<<NP,   256, 0, stream>>>(blk_hist, total, NP);
    k_sbase <<<1,    256, 0, stream>>>(total, sbase, NP);
    k_binoff<<<NP,  NBLK, 0, stream>>>(blk_hist, sbase, blk_off, NP);
    k_split <<<NBLK, 256, 0, stream>>>(src, dst, blk_off, pairs, E, NP);
    k_place <<<NP,   512, 0, stream>>>(pairs, sbase, rowptr, dis, csr_src, N, NP);

    // layer 1 GEMM, then agg layers (2/3 GEMMs fused into agg epilogues)
    k_gemm1<<<gemm_bl, 128, 0, stream>>>(x, W1, dis, hpsA, N);
    k_agg<true ><<<nodes_bl, 256, 0, stream>>>(hpsA, rowptr, csr_src, dis, b1, catb + 0,  N, W2, hpsB);
    k_agg<true ><<<nodes_bl, 256, 0, stream>>>(hpsB, rowptr, csr_src, dis, b2, catb + 32, N, W3, hpsA);
    k_agg<false><<<nodes_bl, 256, 0, stream>>>(hpsA, rowptr, csr_src, dis, b3, catb + 64, N, nullptr, nullptr);

    k_idx<<<(G + 255) / 256, 256, 0, stream>>>(batch, idx, N, G);
    k_head<<<G, 128, 0, stream>>>(catb, idx, l1w, l1b, l2w, l2b, out);
}